// Round 1
// baseline (2755.286 us; speedup 1.0000x reference)
//
#include <hip/hip_runtime.h>

#define NPROJ 360
#define DH 512
#define DW 512
#define VZ 128
#define VY 128
#define VX 128
#define ZC 8   // z-values per thread (accumulators in registers)

__global__ __launch_bounds__(256)
void cone_bp_kernel(const float* __restrict__ sino,     // [NPROJ, DH, DW]
                    const float* __restrict__ origin,   // [3] (z,y,x)
                    const float* __restrict__ spacing,  // [3] (z,y,x)
                    const float* __restrict__ traj,     // [NPROJ, 3, 4]
                    const float* __restrict__ pm_p,     // [1]
                    float* __restrict__ out)            // [VZ, VY, VX]
{
    const int x  = threadIdx.x;                       // 0..127
    const int y  = blockIdx.y * blockDim.y + threadIdx.y; // 0..127
    const int z0 = blockIdx.z * ZC;

    const float oz = origin[0], oy = origin[1], ox = origin[2];
    const float sz = spacing[0], sy = spacing[1], sx = spacing[2];
    const float pm = pm_p[0];

    const float wx  = ox + sx * (float)x;
    const float wy  = oy + sy * (float)y;
    const float wz0 = oz + sz * (float)z0;

    float acc[ZC];
#pragma unroll
    for (int j = 0; j < ZC; ++j) acc[j] = 0.0f;

    const float* P = traj;
    const float* img = sino;
    for (int n = 0; n < NPROJ; ++n, P += 12, img += DH * DW) {
        const float p00 = P[0], p01 = P[1], p02 = P[2],  p03 = P[3];
        const float p10 = P[4], p11 = P[5], p12 = P[6],  p13 = P[7];
        const float p20 = P[8], p21 = P[9], p22 = P[10], p23 = P[11];

        float un = p00 * wx + p01 * wy + p02 * wz0 + p03;
        float vn = p10 * wx + p11 * wy + p12 * wz0 + p13;
        float tt = p20 * wx + p21 * wy + p22 * wz0 + p23;

        if (p02 == 0.0f && p22 == 0.0f) {
            // Circular-orbit fast path: u and 1/t^2 are z-independent; v linear in z.
            const float rt = 1.0f / tt;
            const float u  = un * rt;
            const float w  = pm * rt * rt;
            const bool uval = (u >= 0.0f) && (u <= (float)(DW - 1));
            const float u0f = floorf(u);
            const float fu  = u - u0f;
            const int   u0  = (int)u0f;
            const int u0c = min(max(u0, 0), DW - 1);
            const int u1c = min(max(u0 + 1, 0), DW - 1);
            const float dv = p12 * sz * rt;   // v step per z voxel
            float v = vn * rt;
#pragma unroll
            for (int j = 0; j < ZC; ++j) {
                const float v0f = floorf(v);
                const float fv  = v - v0f;
                const int   v0  = (int)v0f;
                const bool valid = uval && (v >= 0.0f) && (v <= (float)(DH - 1));
                const int v0c = min(max(v0, 0), DH - 1);
                const int v1c = min(max(v0 + 1, 0), DH - 1);
                const float* r0 = img + v0c * DW;
                const float* r1 = img + v1c * DW;
                const float t00 = r0[u0c], t01 = r0[u1c];
                const float t10 = r1[u0c], t11 = r1[u1c];
                const float top = t00 + fu * (t01 - t00);
                const float bot = t10 + fu * (t11 - t10);
                const float s   = top + fv * (bot - top);
                acc[j] += valid ? (s * w) : 0.0f;
                v += dv;
            }
        } else {
            // Generic path (never taken for circular trajectory, kept for correctness).
            const float dun = p02 * sz, dvn = p12 * sz, dtt = p22 * sz;
#pragma unroll
            for (int j = 0; j < ZC; ++j) {
                const float rt = 1.0f / tt;
                const float u = un * rt;
                const float v = vn * rt;
                const float w = pm * rt * rt;
                const bool valid = (u >= 0.0f) && (u <= (float)(DW - 1)) &&
                                   (v >= 0.0f) && (v <= (float)(DH - 1));
                const float u0f = floorf(u), v0f = floorf(v);
                const float fu = u - u0f, fv = v - v0f;
                const int u0 = (int)u0f, v0 = (int)v0f;
                const int u0c = min(max(u0, 0), DW - 1);
                const int u1c = min(max(u0 + 1, 0), DW - 1);
                const int v0c = min(max(v0, 0), DH - 1);
                const int v1c = min(max(v0 + 1, 0), DH - 1);
                const float* r0 = img + v0c * DW;
                const float* r1 = img + v1c * DW;
                const float t00 = r0[u0c], t01 = r0[u1c];
                const float t10 = r1[u0c], t11 = r1[u1c];
                const float top = t00 + fu * (t01 - t00);
                const float bot = t10 + fu * (t11 - t10);
                const float s   = top + fv * (bot - top);
                acc[j] += valid ? (s * w) : 0.0f;
                un += dun; vn += dvn; tt += dtt;
            }
        }
    }

#pragma unroll
    for (int j = 0; j < ZC; ++j) {
        out[((size_t)(z0 + j) * VY + y) * VX + x] = acc[j];
    }
}

extern "C" void kernel_launch(void* const* d_in, const int* in_sizes, int n_in,
                              void* d_out, int out_size, void* d_ws, size_t ws_size,
                              hipStream_t stream) {
    const float* sino    = (const float*)d_in[0];
    // d_in[1] is volume_shape (constant 128^3, hardcoded)
    const float* origin  = (const float*)d_in[2];
    const float* spacing = (const float*)d_in[3];
    const float* traj    = (const float*)d_in[4];
    const float* pm      = (const float*)d_in[5];
    // d_in[6] step_size: unused by the reference math
    float* out = (float*)d_out;

    dim3 block(128, 2, 1);
    dim3 grid(1, VY / 2, VZ / ZC);
    cone_bp_kernel<<<grid, block, 0, stream>>>(sino, origin, spacing, traj, pm, out);
}

// Round 3
// 2291.322 us; speedup vs baseline: 1.2025x; 1.2025x over previous
//
#include <hip/hip_runtime.h>

#define NPROJ 360
#define DH 512
#define DW 512
#define VZ 128
#define VY 128
#define VX 128
#define ZC 8   // z-values per thread

// 4-byte-aligned float2 so the compiler emits global_load_dwordx2 at align 4
// (legal & fast on gfx9+ global address space).
typedef float f2_u __attribute__((ext_vector_type(2), aligned(4)));

__global__ __launch_bounds__(256, 4)
void cone_bp_kernel(const float* __restrict__ sino,     // [NPROJ, DH, DW]
                    const float* __restrict__ origin,   // [3] (z,y,x)
                    const float* __restrict__ spacing,  // [3] (z,y,x)
                    const float* __restrict__ traj,     // [NPROJ, 3, 4]
                    const float* __restrict__ pm_p,     // [1]
                    float* __restrict__ out)            // [VZ, VY, VX]
{
    // Block decode: consecutive blockIdx.x round-robin across the 8 XCDs,
    // so bid&7 selects a z-slab -> each XCD's L2 only caches its v-band.
    const int bid  = blockIdx.x;
    const int slab = bid & 7;          // z-slab (16 z's) -> XCD
    const int rem  = bid >> 3;         // 0..127
    const int zis  = rem & 1;          // which ZC-chunk inside the slab
    const int ypr  = rem >> 1;         // 0..63
    const int x    = threadIdx.x;                  // 0..127
    const int y    = ypr * 2 + threadIdx.y;        // 0..127
    const int z0   = slab * 16 + zis * ZC;

    const float oz = origin[0], oy = origin[1], ox = origin[2];
    const float sz = spacing[0], sy = spacing[1], sx = spacing[2];
    const float pm = pm_p[0];

    const float wx  = ox + sx * (float)x;
    const float wy  = oy + sy * (float)y;
    const float wz0 = oz + sz * (float)z0;

    float acc[ZC];
#pragma unroll
    for (int j = 0; j < ZC; ++j) acc[j] = 0.0f;

    const float* P = traj;
    const float* img = sino;
    for (int n = 0; n < NPROJ; ++n, P += 12, img += DH * DW) {
        const float p00 = P[0], p01 = P[1], p02 = P[2],  p03 = P[3];
        const float p10 = P[4], p11 = P[5], p12 = P[6],  p13 = P[7];
        const float p20 = P[8], p21 = P[9], p22 = P[10], p23 = P[11];

        float un = p00 * wx + p01 * wy + p02 * wz0 + p03;
        float vn = p10 * wx + p11 * wy + p12 * wz0 + p13;
        float tt = p20 * wx + p21 * wy + p22 * wz0 + p23;

        if (p02 == 0.0f && p22 == 0.0f) {
            // Circular-orbit fast path: u and 1/t^2 z-independent; v linear in z.
            const float rt = 1.0f / tt;
            const float u  = un * rt;
            const float w  = pm * rt * rt;
            const bool uval = (u >= 0.0f) && (u <= (float)(DW - 1));
            const float u0f = floorf(u);
            const float fu  = u - u0f;
            const int   u0  = (int)u0f;
            const int u0c = min(max(u0, 0), DW - 1);
            const int u1c = min(max(u0 + 1, 0), DW - 1);
            const int uc  = min(max(u0, 0), DW - 2);   // float2 load column
            const bool s0 = (u0c == uc);               // t00 from .x ?
            const bool s1 = (u1c == uc);               // t01 from .x ?
            const float dv = p12 * sz * rt;            // v step per z voxel
            float v = vn * rt;

            f2_u  pr0[ZC], pr1[ZC];
            float fv[ZC];
            bool  valid[ZC];
            // Phase 1: issue all 2*ZC packed gathers (max MLP).
#pragma unroll
            for (int j = 0; j < ZC; ++j) {
                const float v0f = floorf(v);
                fv[j] = v - v0f;
                const int v0 = (int)v0f;
                valid[j] = uval && (v >= 0.0f) && (v <= (float)(DH - 1));
                const int v0c = min(max(v0, 0), DH - 1);
                const int v1c = min(max(v0 + 1, 0), DH - 1);
                pr0[j] = *(const f2_u*)(img + v0c * DW + uc);
                pr1[j] = *(const f2_u*)(img + v1c * DW + uc);
                v += dv;
            }
            // Phase 2: combine.
#pragma unroll
            for (int j = 0; j < ZC; ++j) {
                const float t00 = s0 ? pr0[j].x : pr0[j].y;
                const float t01 = s1 ? pr0[j].x : pr0[j].y;
                const float t10 = s0 ? pr1[j].x : pr1[j].y;
                const float t11 = s1 ? pr1[j].x : pr1[j].y;
                const float top = t00 + fu * (t01 - t00);
                const float bot = t10 + fu * (t11 - t10);
                const float s   = top + fv[j] * (bot - top);
                acc[j] += valid[j] ? (s * w) : 0.0f;
            }
        } else {
            // Generic path (not taken for circular trajectory; correctness fallback).
            const float dun = p02 * sz, dvn = p12 * sz, dtt = p22 * sz;
            float unj = un, vnj = vn, ttj = tt;
#pragma unroll
            for (int j = 0; j < ZC; ++j) {
                const float rt = 1.0f / ttj;
                const float u = unj * rt;
                const float v = vnj * rt;
                const float w = pm * rt * rt;
                const bool valid = (u >= 0.0f) && (u <= (float)(DW - 1)) &&
                                   (v >= 0.0f) && (v <= (float)(DH - 1));
                const float u0f = floorf(u), v0f = floorf(v);
                const float fu = u - u0f, fv = v - v0f;
                const int u0 = (int)u0f, v0 = (int)v0f;
                const int u0c = min(max(u0, 0), DW - 1);
                const int u1c = min(max(u0 + 1, 0), DW - 1);
                const int v0c = min(max(v0, 0), DH - 1);
                const int v1c = min(max(v0 + 1, 0), DH - 1);
                const float* r0 = img + v0c * DW;
                const float* r1 = img + v1c * DW;
                const float t00 = r0[u0c], t01 = r0[u1c];
                const float t10 = r1[u0c], t11 = r1[u1c];
                const float top = t00 + fu * (t01 - t00);
                const float bot = t10 + fu * (t11 - t10);
                const float s   = top + fv * (bot - top);
                acc[j] += valid ? (s * w) : 0.0f;
                unj += dun; vnj += dvn; ttj += dtt;
            }
        }
    }

#pragma unroll
    for (int j = 0; j < ZC; ++j) {
        out[((size_t)(z0 + j) * VY + y) * VX + x] = acc[j];
    }
}

extern "C" void kernel_launch(void* const* d_in, const int* in_sizes, int n_in,
                              void* d_out, int out_size, void* d_ws, size_t ws_size,
                              hipStream_t stream) {
    const float* sino    = (const float*)d_in[0];
    const float* origin  = (const float*)d_in[2];
    const float* spacing = (const float*)d_in[3];
    const float* traj    = (const float*)d_in[4];
    const float* pm      = (const float*)d_in[5];
    float* out = (float*)d_out;

    dim3 block(128, 2, 1);
    dim3 grid(1024, 1, 1);   // 1D; kernel decodes (y, z-slab) with XCD swizzle
    cone_bp_kernel<<<grid, block, 0, stream>>>(sino, origin, spacing, traj, pm, out);
}